// Round 5
// baseline (422.345 us; speedup 1.0000x reference)
//
#include <hip/hip_runtime.h>
#include <stdint.h>

#define MDIM 4096
#define KDIM 4096
#define NDIM 11008
#define KP   (KDIM/8)   // 512 packed int32 per N-row
#define NKT  (KDIM/64)  // 64 K-steps of BK=64

typedef float  f32x4   __attribute__((ext_vector_type(4)));
typedef float  f32x16  __attribute__((ext_vector_type(16)));
typedef __bf16 bf16x8  __attribute__((ext_vector_type(8)));
typedef unsigned short u16x8 __attribute__((ext_vector_type(8)));

// RNE f32 -> bf16 bits (matches jax astype(bf16) for non-NaN inputs)
__device__ __forceinline__ unsigned short f2bf(float f) {
  uint32_t u = __builtin_bit_cast(uint32_t, f);
  u += 0x7FFFu + ((u >> 16) & 1u);
  return (unsigned short)(u >> 16);
}
__device__ __forceinline__ float bf2f(unsigned short h) {
  return __builtin_bit_cast(float, (uint32_t)h << 16);
}
__device__ __forceinline__ float bf16r(float f) { return bf2f(f2bf(f)); }

// async global -> LDS, 16B per lane, wave-uniform LDS base + lane*16
__device__ __forceinline__ void lds16(const void* g, void* l) {
  __builtin_amdgcn_global_load_lds(
      (const __attribute__((address_space(1))) unsigned int*)g,
      (__attribute__((address_space(3))) unsigned int*)l, 16, 0, 0);
}

// ---------------- pre-pass 1: dequant packed int4 -> bf16 W[N][K] -----------
__global__ __launch_bounds__(256) void dequant_w_kernel(
    const uint32_t* __restrict__ wq, const float* __restrict__ scales,
    const float* __restrict__ zeros, u16x8* __restrict__ Wbf) {
  int idx = blockIdx.x * 256 + threadIdx.x;      // [0, N*KP)
  int n = idx >> 9;                              // idx / 512
  float s = bf16r(scales[n]);
  float z = bf16r(zeros[n]);
  uint32_t w = wq[idx];
  u16x8 v;
#pragma unroll
  for (int j = 0; j < 8; ++j) {
    float qf = (float)((w >> (4 * j)) & 0xF);
    float t  = bf16r(qf * s);                    // bf16 mul rounding
    v[j] = f2bf(t + z);                          // bf16 add rounding
  }
  Wbf[idx] = v;
}

// ---------------- pre-pass 2: x f32 -> bf16 ---------------------------------
__global__ __launch_bounds__(256) void convert_x_kernel(
    const float4* __restrict__ x, u16x8* __restrict__ Xbf) {
  int idx = blockIdx.x * 256 + threadIdx.x;
  float4 a = x[2 * idx], b = x[2 * idx + 1];
  u16x8 v;
  v[0] = f2bf(a.x); v[1] = f2bf(a.y); v[2] = f2bf(a.z); v[3] = f2bf(a.w);
  v[4] = f2bf(b.x); v[5] = f2bf(b.y); v[6] = f2bf(b.z); v[7] = f2bf(b.w);
  Xbf[idx] = v;
}

// ---------------- main GEMM: 256x256, BK=64, 8 waves, 32x32x16 MFMA ---------
// Same ring/slot/vmcnt schedule as round 3 (traced + passing). Changes:
// (1) MFMA shape 16x16x32 -> 32x32x16 (+20% FLOP/cyc pipe rate, 32 MFMA/tile
//     instead of 128). Per-wave output 128x64 = 4 m-frags x 2 n-frags of
//     32x32, acc = 8 x f32x16.
// (2) m201-faithful phase ordering: ds_reads issued BEFORE the opening
//     barrier (serviced during barrier-arrival skew, overlapping straggler
//     MFMAs of the previous phase), then barrier; lgkmcnt(0); MFMA; barrier.
// LDS layout unchanged: slot = 16 subtiles of 16r x 32k (1KB, st_16x32
// swizzle); A ring 4 x 16KB at 0, B ring at +64KB. 32-row fragments read two
// stacked subtiles; ks parity toggles byte-bit5, which commutes with the
// swizzle XOR (read addr for ks=1 is addr(ks=0) ^ 32).
__global__ __launch_bounds__(512, 2) void gemm256_kernel(
    const unsigned short* __restrict__ Abf,
    const unsigned short* __restrict__ Bbf,
    const float* __restrict__ bias, float* __restrict__ out) {
  __shared__ __align__(16) char smem[131072];

  const int tid  = threadIdx.x;
  const int lane = tid & 63;
  const int wave = tid >> 6;     // 0..7
  const int wm   = wave >> 2;    // 0..1 : M half (128 rows)
  const int wn   = wave & 3;     // 0..3 : N quarter (64 cols)

  // XCD-aware bijective swizzle: 688 = 8 * 86 blocks.
  const int b   = blockIdx.x;
  const int swz = (b & 7) * 86 + (b >> 3);
  const int mt  = swz / 43;
  const int nt  = swz - mt * 43;
  const int bm0 = mt * 256, bn0 = nt * 256;

  // staging: inverse st_16x32 permutation on the SOURCE (round-1 verified)
  const int lp   = (lane >= 32) ? (lane ^ 2) : lane;
  const int srow = lp >> 2;        // 0..15
  const int scol = (lp & 3) << 3;  // 0,8,16,24 (bf16 elems)
  const unsigned short* aR = Abf + (size_t)(bm0 + wave * 32 + srow) * KDIM + scol;
  const unsigned short* bR = Bbf + (size_t)(bn0 + wave * 32 + srow) * KDIM + scol;

  // 32x32x16 fragment read offset (ks=0); ks=1 address = this ^ 32.
  // lane covers row r31 = lane&31 (spans 2 subtiles), k = (lane>>5)*8.
  const int r31  = lane & 31;
  const int sub  = r31 >> 4;
  const int r15  = r31 & 15;
  const int kb   = (lane >> 5) << 4;        // 0 or 16 bytes
  const int swzb = (r15 >> 3) & 1;          // st_16x32: flip bit5 when row bit3
  const int rd0  = sub * 1024 + r15 * 64 + kb + swzb * 32;
  const int rd1  = rd0 ^ 32;

  const int aoffc = wm * 8192;          // wm*8 subtiles (128 rows)
  const int boffc = 65536 + wn * 4096;  // B ring + wn*4 subtiles (64 rows)

  f32x16 acc[4][2];
#pragma unroll
  for (int i = 0; i < 4; ++i)
#pragma unroll
    for (int j = 0; j < 2; ++j)
#pragma unroll
      for (int r = 0; r < 16; ++r) acc[i][j][r] = 0.f;

  bf16x8 Af[4], Bf[2];

#define STAGE_HALF(srcR, ringoff, tile, ks, slot)                           \
  do {                                                                      \
    const unsigned short* s_ = (srcR) + (size_t)((tile) * 64 + (ks) * 32);  \
    char* d_ = smem + (ringoff) + ((slot) << 14) + wave * 2048;             \
    lds16(s_, d_);                                                          \
    lds16(s_ + (size_t)16 * KDIM, d_ + 1024);                               \
  } while (0)

#define READ6(slotbase, KS)                                                 \
  do {                                                                      \
    const int ro_ = (KS) ? rd1 : rd0;                                       \
    _Pragma("unroll") for (int mf = 0; mf < 4; ++mf)                        \
        Af[mf] = *(const bf16x8*)(smem + aoffc + (slotbase) +               \
                                  mf * 2048 + ro_);                         \
    _Pragma("unroll") for (int nf = 0; nf < 2; ++nf)                        \
        Bf[nf] = *(const bf16x8*)(smem + boffc + (slotbase) +               \
                                  nf * 2048 + ro_);                         \
  } while (0)

#define MFMA8()                                                             \
  __builtin_amdgcn_s_setprio(1);                                            \
  _Pragma("unroll") for (int mf = 0; mf < 4; ++mf)                          \
      _Pragma("unroll") for (int nf = 0; nf < 2; ++nf)                      \
          acc[mf][nf] = __builtin_amdgcn_mfma_f32_32x32x16_bf16(            \
              Af[mf], Bf[nf], acc[mf][nf], 0, 0, 0);                        \
  __builtin_amdgcn_s_setprio(0);

#define BAR                                                                 \
  __builtin_amdgcn_s_barrier();                                             \
  __builtin_amdgcn_sched_barrier(0);

#define SB0 __builtin_amdgcn_sched_barrier(0);

#define LGKM0                                                               \
  asm volatile("s_waitcnt lgkmcnt(0)" ::: "memory");                        \
  __builtin_amdgcn_sched_barrier(0);

#define VMWAIT(N) asm volatile("s_waitcnt vmcnt(" #N ")" ::: "memory")

  // One phase = one ks16 step: {READ6 | STAGE | [vmcnt] | BAR | lgkm0 |
  // 8x MFMA | BAR}. Slot schedule identical to round 3 (traced):
  // S0s/S1s = slots of (T, ks-half0/1); SN1s = slot for (T+1,h1) staging;
  // (T+2,h0) recycles into S0s. VMWAIT(8) at p1 retires s1 for p2; at p3
  // retires next tile's s0.
#define TILE(T, S0s, S1s, SN1s, NSTG, VM1STMT, VM3STMT)                     \
  do {                                                                      \
    /* p0: ks16=0 (slot s0 low half) */                                     \
    READ6((S0s) << 14, 0);                                                  \
    if ((NSTG) >= 1) STAGE_HALF(aR, 0, (T) + 1, 1, SN1s);                   \
    SB0; BAR; LGKM0; MFMA8(); BAR;                                          \
    /* p1: ks16=1 */                                                        \
    READ6((S0s) << 14, 1);                                                  \
    if ((NSTG) >= 2) STAGE_HALF(bR, 65536, (T) + 1, 1, SN1s);               \
    VM1STMT;                                                                \
    SB0; BAR; LGKM0; MFMA8(); BAR;                                          \
    /* p2: ks16=2 (slot s1 low half) */                                     \
    READ6((S1s) << 14, 0);                                                  \
    if ((NSTG) >= 3) STAGE_HALF(aR, 0, (T) + 2, 0, S0s);                    \
    SB0; BAR; LGKM0; MFMA8(); BAR;                                          \
    /* p3: ks16=3 */                                                        \
    READ6((S1s) << 14, 1);                                                  \
    if ((NSTG) >= 4) STAGE_HALF(bR, 65536, (T) + 2, 0, S0s);                \
    VM3STMT;                                                                \
    SB0; BAR; LGKM0; MFMA8(); BAR;                                          \
  } while (0)

  // prologue: A0(0),B0(0),A1(0),B1(0),A0(1),B0(1) = 12 loads; wait first 4
  STAGE_HALF(aR, 0, 0, 0, 0);
  STAGE_HALF(bR, 65536, 0, 0, 0);
  STAGE_HALF(aR, 0, 0, 1, 1);
  STAGE_HALF(bR, 65536, 0, 1, 1);
  STAGE_HALF(aR, 0, 1, 0, 2);
  STAGE_HALF(bR, 65536, 1, 0, 2);
  VMWAIT(8);
  BAR;

  for (int tt = 0; tt < 62; tt += 2) {
    TILE(tt,     0, 1, 3, 4, VMWAIT(8), VMWAIT(8));
    TILE(tt + 1, 2, 3, 1, 4, VMWAIT(8), VMWAIT(8));
  }
  // t=62: stage only A1(63),B1(63); t=63: no staging, drain at p1
  TILE(62, 0, 1, 3, 2, VMWAIT(8), VMWAIT(4));
  TILE(63, 2, 3, 1, 0, VMWAIT(0), (void)0);

#undef TILE
#undef VMWAIT
#undef LGKM0
#undef SB0
#undef BAR
#undef MFMA8
#undef READ6
#undef STAGE_HALF

  // epilogue: 32x32 C/D layout: col = lane&31,
  // row = (reg&3) + 8*(reg>>2) + 4*(lane>>5)   [m74/m101 verified]
  const int colv = bn0 + wn * 64 + (lane & 31);
  const int rowb = bm0 + wm * 128 + ((lane >> 5) << 2);
  float bv[2];
  bv[0] = bias[colv];
  bv[1] = bias[colv + 32];
#pragma unroll
  for (int mf = 0; mf < 4; ++mf)
#pragma unroll
    for (int nf = 0; nf < 2; ++nf)
#pragma unroll
      for (int reg = 0; reg < 16; ++reg) {
        int row = rowb + mf * 32 + (reg & 3) + ((reg >> 2) << 3);
        out[(size_t)row * NDIM + colv + nf * 32] = acc[mf][nf][reg] + bv[nf];
      }
}

// ---------------- fallback fused 128x128 kernel (ws too small) --------------
__global__ __launch_bounds__(256, 3) void gemm_fused_kernel(
    const float* __restrict__ x, const uint32_t* __restrict__ wq,
    const float* __restrict__ scales, const float* __restrict__ zeros,
    const float* __restrict__ bias, float* __restrict__ out) {
  __shared__ __align__(16) char smem[2 * 128 * 64 * 2];
  char* As = smem;
  char* Bs = smem + 16384;

  const int tid  = threadIdx.x;
  const int lane = tid & 63;
  const int wave = tid >> 6;
  const int wm = wave >> 1, wn = wave & 1;

  const int b   = blockIdx.x;
  const int swz = (b & 7) * 344 + (b >> 3);
  const int mt  = swz / 86;
  const int nt  = swz - mt * 86;
  const int bm0 = mt * 128, bn0 = nt * 128;

  f32x4 acc[4][4];
#pragma unroll
  for (int i = 0; i < 4; ++i)
#pragma unroll
    for (int j = 0; j < 4; ++j) acc[i][j] = (f32x4){0.f, 0.f, 0.f, 0.f};

  const int base_a = ((wm * 64 + (lane & 15)) << 7) + ((lane >> 4) << 4);
  const int base_b = ((wn * 64 + (lane & 15)) << 7) + ((lane >> 4) << 4);

  float sv[4], zv[4];
#pragma unroll
  for (int it = 0; it < 4; ++it) {
    int r = bn0 + it * 32 + (tid >> 3);
    sv[it] = bf16r(scales[r]);
    zv[it] = bf16r(zeros[r]);
  }

  for (int kt = 0; kt < KDIM / 64; ++kt) {
    const int k0 = kt * 64;
    __syncthreads();
#pragma unroll
    for (int it = 0; it < 4; ++it) {
      int ch = it * 256 + tid;
      int row = ch >> 3, c8 = ch & 7;
      const float* src = x + (size_t)(bm0 + row) * KDIM + k0 + c8 * 8;
      float4 f0 = *(const float4*)src;
      float4 f1 = *(const float4*)(src + 4);
      u16x8 v;
      v[0] = f2bf(f0.x); v[1] = f2bf(f0.y); v[2] = f2bf(f0.z); v[3] = f2bf(f0.w);
      v[4] = f2bf(f1.x); v[5] = f2bf(f1.y); v[6] = f2bf(f1.z); v[7] = f2bf(f1.w);
      *(u16x8*)(As + row * 128 + c8 * 16) = v;
    }
#pragma unroll
    for (int it = 0; it < 4; ++it) {
      int ch = it * 256 + tid;
      int row = ch >> 3, kp = ch & 7;
      uint32_t w = wq[(size_t)(bn0 + row) * KP + kt * 8 + kp];
      float s = sv[it], z = zv[it];
      u16x8 v;
#pragma unroll
      for (int j = 0; j < 8; ++j) {
        float qf = (float)((w >> (4 * j)) & 0xF);
        float t  = bf16r(qf * s);
        v[j] = f2bf(t + z);
      }
      *(u16x8*)(Bs + row * 128 + kp * 16) = v;
    }
    __syncthreads();
#pragma unroll
    for (int ks = 0; ks < 2; ++ks) {
      bf16x8 af[4], bf[4];
#pragma unroll
      for (int i = 0; i < 4; ++i)
        af[i] = *(const bf16x8*)(As + base_a + i * 2048 + ks * 64);
#pragma unroll
      for (int j = 0; j < 4; ++j)
        bf[j] = *(const bf16x8*)(Bs + base_b + j * 2048 + ks * 64);
#pragma unroll
      for (int i = 0; i < 4; ++i)
#pragma unroll
        for (int j = 0; j < 4; ++j)
          acc[i][j] = __builtin_amdgcn_mfma_f32_16x16x32_bf16(af[i], bf[j],
                                                              acc[i][j], 0, 0, 0);
    }
  }

  const int colbase = bn0 + wn * 64 + (lane & 15);
  const int rowbase = bm0 + wm * 64 + ((lane >> 4) << 2);
  float bv[4];
#pragma unroll
  for (int j = 0; j < 4; ++j) bv[j] = bias[colbase + j * 16];
#pragma unroll
  for (int i = 0; i < 4; ++i) {
#pragma unroll
    for (int j = 0; j < 4; ++j) {
      size_t base = (size_t)(rowbase + i * 16) * NDIM + colbase + j * 16;
#pragma unroll
      for (int r = 0; r < 4; ++r)
        out[base + (size_t)r * NDIM] = acc[i][j][r] + bv[j];
    }
  }
}

extern "C" void kernel_launch(void* const* d_in, const int* in_sizes, int n_in,
                              void* d_out, int out_size, void* d_ws, size_t ws_size,
                              hipStream_t stream) {
  const float*    x      = (const float*)d_in[0];
  const uint32_t* wq     = (const uint32_t*)d_in[1];
  const float*    scales = (const float*)d_in[2];
  const float*    zeros  = (const float*)d_in[3];
  const float*    bias   = (const float*)d_in[4];
  float*          out    = (float*)d_out;

  const size_t needW = (size_t)NDIM * KDIM * 2;  // 90,177,536 B
  const size_t needX = (size_t)MDIM * KDIM * 2;  // 33,554,432 B

  if (ws_size >= needW + needX) {
    unsigned short* Wbf = (unsigned short*)d_ws;
    unsigned short* Xbf = (unsigned short*)((char*)d_ws + needW);
    dequant_w_kernel<<<(NDIM * KP) / 256, 256, 0, stream>>>(wq, scales, zeros,
                                                            (u16x8*)Wbf);
    convert_x_kernel<<<(MDIM * KDIM / 8) / 256, 256, 0, stream>>>(
        (const float4*)x, (u16x8*)Xbf);
    gemm256_kernel<<<688, 512, 0, stream>>>(Xbf, Wbf, bias, out);
  } else {
    gemm_fused_kernel<<<2752, 256, 0, stream>>>(x, wq, scales, zeros, bias, out);
  }
}

// Round 6
// 403.990 us; speedup vs baseline: 1.0454x; 1.0454x over previous
//
#include <hip/hip_runtime.h>
#include <stdint.h>

#define MDIM 4096
#define KDIM 4096
#define NDIM 11008
#define KP   (KDIM/8)   // 512 packed int32 per N-row
#define NKT  (KDIM/64)  // 64 K-steps of BK=64

typedef float  f32x4   __attribute__((ext_vector_type(4)));
typedef float  f32x16  __attribute__((ext_vector_type(16)));
typedef __bf16 bf16x8  __attribute__((ext_vector_type(8)));
typedef unsigned short u16x8 __attribute__((ext_vector_type(8)));

// RNE f32 -> bf16 bits (matches jax astype(bf16) for non-NaN inputs)
__device__ __forceinline__ unsigned short f2bf(float f) {
  uint32_t u = __builtin_bit_cast(uint32_t, f);
  u += 0x7FFFu + ((u >> 16) & 1u);
  return (unsigned short)(u >> 16);
}
__device__ __forceinline__ float bf2f(unsigned short h) {
  return __builtin_bit_cast(float, (uint32_t)h << 16);
}
__device__ __forceinline__ float bf16r(float f) { return bf2f(f2bf(f)); }

// async global -> LDS, 16B per lane, wave-uniform LDS base + lane*16
__device__ __forceinline__ void lds16(const void* g, void* l) {
  __builtin_amdgcn_global_load_lds(
      (const __attribute__((address_space(1))) unsigned int*)g,
      (__attribute__((address_space(3))) unsigned int*)l, 16, 0, 0);
}

// ---------------- pre-pass 1: dequant packed int4 -> bf16 W[N][K] -----------
__global__ __launch_bounds__(256) void dequant_w_kernel(
    const uint32_t* __restrict__ wq, const float* __restrict__ scales,
    const float* __restrict__ zeros, u16x8* __restrict__ Wbf) {
  int idx = blockIdx.x * 256 + threadIdx.x;      // [0, N*KP)
  int n = idx >> 9;                              // idx / 512
  float s = bf16r(scales[n]);
  float z = bf16r(zeros[n]);
  uint32_t w = wq[idx];
  u16x8 v;
#pragma unroll
  for (int j = 0; j < 8; ++j) {
    float qf = (float)((w >> (4 * j)) & 0xF);
    float t  = bf16r(qf * s);                    // bf16 mul rounding
    v[j] = f2bf(t + z);                          // bf16 add rounding
  }
  Wbf[idx] = v;
}

// ---------------- pre-pass 2: x f32 -> bf16 ---------------------------------
__global__ __launch_bounds__(256) void convert_x_kernel(
    const float4* __restrict__ x, u16x8* __restrict__ Xbf) {
  int idx = blockIdx.x * 256 + threadIdx.x;
  float4 a = x[2 * idx], b = x[2 * idx + 1];
  u16x8 v;
  v[0] = f2bf(a.x); v[1] = f2bf(a.y); v[2] = f2bf(a.z); v[3] = f2bf(a.w);
  v[4] = f2bf(b.x); v[5] = f2bf(b.y); v[6] = f2bf(b.z); v[7] = f2bf(b.w);
  Xbf[idx] = v;
}

// ---------------- main GEMM: 256x256, BK=64, 8 waves, 32x32x16 MFMA ---------
// Round-5 structure with the bank-conflict fix: odd subtiles (rows 16-31 of
// each 32-row group) are stored with byte-bit4 flipped (the two 16B k-slots
// of each row swapped), realized by sourcing the second lds16 from scol^8;
// reads XOR bit4 by sub = (row>>4)&1. Bank-quad class of a lane's b128 read
// becomes 4*(r15%2) + ((h^sub) ^ 2*swzb): each 16-lane group covers 4
// distinct classes, each 32-lane window all 8 evenly — the same balance as
// the round-3 pattern that measured ZERO conflicts. Round 5's pattern had
// bit4 = h only (2 values) -> even/odd class imbalance -> 3.4e7 conflicts.
__global__ __launch_bounds__(512, 2) void gemm256_kernel(
    const unsigned short* __restrict__ Abf,
    const unsigned short* __restrict__ Bbf,
    const float* __restrict__ bias, float* __restrict__ out) {
  __shared__ __align__(16) char smem[131072];

  const int tid  = threadIdx.x;
  const int lane = tid & 63;
  const int wave = tid >> 6;     // 0..7
  const int wm   = wave >> 2;    // 0..1 : M half (128 rows)
  const int wn   = wave & 3;     // 0..3 : N quarter (64 cols)

  // XCD-aware bijective swizzle: 688 = 8 * 86 blocks.
  const int b   = blockIdx.x;
  const int swz = (b & 7) * 86 + (b >> 3);
  const int mt  = swz / 43;
  const int nt  = swz - mt * 43;
  const int bm0 = mt * 256, bn0 = nt * 256;

  // staging: inverse st_16x32 permutation on the SOURCE (round-1 verified).
  // Second lds16 of each STAGE_HALF (odd subtile) additionally swaps the two
  // 16B k-slots per row: source col ^ 8 elems  <=>  stored byte ^ 16.
  const int lp   = (lane >= 32) ? (lane ^ 2) : lane;
  const int srow = lp >> 2;        // 0..15
  const int scol = (lp & 3) << 3;  // 0,8,16,24 (bf16 elems)
  const unsigned short* aR  = Abf + (size_t)(bm0 + wave * 32 + srow) * KDIM + scol;
  const unsigned short* aR2 = Abf + (size_t)(bm0 + wave * 32 + 16 + srow) * KDIM + (scol ^ 8);
  const unsigned short* bR  = Bbf + (size_t)(bn0 + wave * 32 + srow) * KDIM + scol;
  const unsigned short* bR2 = Bbf + (size_t)(bn0 + wave * 32 + 16 + srow) * KDIM + (scol ^ 8);

  // 32x32x16 fragment read offset (ks16=0); ks16=1 address = this ^ 32.
  // lane covers row r31 = lane&31 (spans 2 subtiles), k-half h = lane>>5.
  // byte = sub*1024 + r15*64 + (h*16 ^ sub*16) + swzb*32  (all fields disjoint)
  const int r31  = lane & 31;
  const int sub  = r31 >> 4;
  const int r15  = r31 & 15;
  const int kb   = (lane >> 5) << 4;        // 0 or 16 bytes
  const int swzb = (r15 >> 3) & 1;          // st_16x32: flip bit5 when row bit3
  const int rd0  = sub * 1024 + r15 * 64 + (kb ^ (sub << 4)) + swzb * 32;
  const int rd1  = rd0 ^ 32;

  const int aoffc = wm * 8192;          // wm*8 subtiles (128 rows)
  const int boffc = 65536 + wn * 4096;  // B ring + wn*4 subtiles (64 rows)

  f32x16 acc[4][2];
#pragma unroll
  for (int i = 0; i < 4; ++i)
#pragma unroll
    for (int j = 0; j < 2; ++j)
#pragma unroll
      for (int r = 0; r < 16; ++r) acc[i][j][r] = 0.f;

  bf16x8 Af[4], Bf[2];

#define STAGE_HALF(R1, R2, ringoff, tile, ks, slot)                         \
  do {                                                                      \
    const size_t ko_ = (size_t)((tile) * 64 + (ks) * 32);                   \
    char* d_ = smem + (ringoff) + ((slot) << 14) + wave * 2048;             \
    lds16((R1) + ko_, d_);                                                  \
    lds16((R2) + ko_, d_ + 1024);                                           \
  } while (0)

#define READ6(slotbase, KS)                                                 \
  do {                                                                      \
    const int ro_ = (KS) ? rd1 : rd0;                                       \
    _Pragma("unroll") for (int mf = 0; mf < 4; ++mf)                        \
        Af[mf] = *(const bf16x8*)(smem + aoffc + (slotbase) +               \
                                  mf * 2048 + ro_);                         \
    _Pragma("unroll") for (int nf = 0; nf < 2; ++nf)                        \
        Bf[nf] = *(const bf16x8*)(smem + boffc + (slotbase) +               \
                                  nf * 2048 + ro_);                         \
  } while (0)

#define MFMA8()                                                             \
  __builtin_amdgcn_s_setprio(1);                                            \
  _Pragma("unroll") for (int mf = 0; mf < 4; ++mf)                          \
      _Pragma("unroll") for (int nf = 0; nf < 2; ++nf)                      \
          acc[mf][nf] = __builtin_amdgcn_mfma_f32_32x32x16_bf16(            \
              Af[mf], Bf[nf], acc[mf][nf], 0, 0, 0);                        \
  __builtin_amdgcn_s_setprio(0);

#define BAR                                                                 \
  __builtin_amdgcn_s_barrier();                                             \
  __builtin_amdgcn_sched_barrier(0);

#define SB0 __builtin_amdgcn_sched_barrier(0);

#define LGKM0                                                               \
  asm volatile("s_waitcnt lgkmcnt(0)" ::: "memory");                        \
  __builtin_amdgcn_sched_barrier(0);

#define VMWAIT(N) asm volatile("s_waitcnt vmcnt(" #N ")" ::: "memory")

  // One phase = one ks16 step: {READ6 | STAGE | [vmcnt] | BAR | lgkm0 |
  // 8x MFMA | BAR}. Slot schedule identical to round 3 (traced):
  // S0s/S1s = slots of (T, ks-half0/1); SN1s = slot for (T+1,h1) staging;
  // (T+2,h0) recycles into S0s. VMWAIT(8) at p1 retires s1 for p2; at p3
  // retires next tile's s0.
#define TILE(T, S0s, S1s, SN1s, NSTG, VM1STMT, VM3STMT)                     \
  do {                                                                      \
    /* p0: ks16=0 (slot s0 low half) */                                     \
    READ6((S0s) << 14, 0);                                                  \
    if ((NSTG) >= 1) STAGE_HALF(aR, aR2, 0, (T) + 1, 1, SN1s);              \
    SB0; BAR; LGKM0; MFMA8(); BAR;                                          \
    /* p1: ks16=1 */                                                        \
    READ6((S0s) << 14, 1);                                                  \
    if ((NSTG) >= 2) STAGE_HALF(bR, bR2, 65536, (T) + 1, 1, SN1s);          \
    VM1STMT;                                                                \
    SB0; BAR; LGKM0; MFMA8(); BAR;                                          \
    /* p2: ks16=2 (slot s1 low half) */                                     \
    READ6((S1s) << 14, 0);                                                  \
    if ((NSTG) >= 3) STAGE_HALF(aR, aR2, 0, (T) + 2, 0, S0s);               \
    SB0; BAR; LGKM0; MFMA8(); BAR;                                          \
    /* p3: ks16=3 */                                                        \
    READ6((S1s) << 14, 1);                                                  \
    if ((NSTG) >= 4) STAGE_HALF(bR, bR2, 65536, (T) + 2, 0, S0s);           \
    VM3STMT;                                                                \
    SB0; BAR; LGKM0; MFMA8(); BAR;                                          \
  } while (0)

  // prologue: A0(0),B0(0),A1(0),B1(0),A0(1),B0(1) = 12 loads; wait first 4
  STAGE_HALF(aR, aR2, 0, 0, 0, 0);
  STAGE_HALF(bR, bR2, 65536, 0, 0, 0);
  STAGE_HALF(aR, aR2, 0, 0, 1, 1);
  STAGE_HALF(bR, bR2, 65536, 0, 1, 1);
  STAGE_HALF(aR, aR2, 0, 1, 0, 2);
  STAGE_HALF(bR, bR2, 65536, 1, 0, 2);
  VMWAIT(8);
  BAR;

  for (int tt = 0; tt < 62; tt += 2) {
    TILE(tt,     0, 1, 3, 4, VMWAIT(8), VMWAIT(8));
    TILE(tt + 1, 2, 3, 1, 4, VMWAIT(8), VMWAIT(8));
  }
  // t=62: stage only A1(63),B1(63); t=63: no staging, drain at p1
  TILE(62, 0, 1, 3, 2, VMWAIT(8), VMWAIT(4));
  TILE(63, 2, 3, 1, 0, VMWAIT(0), (void)0);

#undef TILE
#undef VMWAIT
#undef LGKM0
#undef SB0
#undef BAR
#undef MFMA8
#undef READ6
#undef STAGE_HALF

  // epilogue: 32x32 C/D layout: col = lane&31,
  // row = (reg&3) + 8*(reg>>2) + 4*(lane>>5)   [m74/m101 verified]
  const int colv = bn0 + wn * 64 + (lane & 31);
  const int rowb = bm0 + wm * 128 + ((lane >> 5) << 2);
  float bv[2];
  bv[0] = bias[colv];
  bv[1] = bias[colv + 32];
#pragma unroll
  for (int mf = 0; mf < 4; ++mf)
#pragma unroll
    for (int nf = 0; nf < 2; ++nf)
#pragma unroll
      for (int reg = 0; reg < 16; ++reg) {
        int row = rowb + mf * 32 + (reg & 3) + ((reg >> 2) << 3);
        out[(size_t)row * NDIM + colv + nf * 32] = acc[mf][nf][reg] + bv[nf];
      }
}

// ---------------- fallback fused 128x128 kernel (ws too small) --------------
__global__ __launch_bounds__(256, 3) void gemm_fused_kernel(
    const float* __restrict__ x, const uint32_t* __restrict__ wq,
    const float* __restrict__ scales, const float* __restrict__ zeros,
    const float* __restrict__ bias, float* __restrict__ out) {
  __shared__ __align__(16) char smem[2 * 128 * 64 * 2];
  char* As = smem;
  char* Bs = smem + 16384;

  const int tid  = threadIdx.x;
  const int lane = tid & 63;
  const int wave = tid >> 6;
  const int wm = wave >> 1, wn = wave & 1;

  const int b   = blockIdx.x;
  const int swz = (b & 7) * 344 + (b >> 3);
  const int mt  = swz / 86;
  const int nt  = swz - mt * 86;
  const int bm0 = mt * 128, bn0 = nt * 128;

  f32x4 acc[4][4];
#pragma unroll
  for (int i = 0; i < 4; ++i)
#pragma unroll
    for (int j = 0; j < 4; ++j) acc[i][j] = (f32x4){0.f, 0.f, 0.f, 0.f};

  const int base_a = ((wm * 64 + (lane & 15)) << 7) + ((lane >> 4) << 4);
  const int base_b = ((wn * 64 + (lane & 15)) << 7) + ((lane >> 4) << 4);

  float sv[4], zv[4];
#pragma unroll
  for (int it = 0; it < 4; ++it) {
    int r = bn0 + it * 32 + (tid >> 3);
    sv[it] = bf16r(scales[r]);
    zv[it] = bf16r(zeros[r]);
  }

  for (int kt = 0; kt < KDIM / 64; ++kt) {
    const int k0 = kt * 64;
    __syncthreads();
#pragma unroll
    for (int it = 0; it < 4; ++it) {
      int ch = it * 256 + tid;
      int row = ch >> 3, c8 = ch & 7;
      const float* src = x + (size_t)(bm0 + row) * KDIM + k0 + c8 * 8;
      float4 f0 = *(const float4*)src;
      float4 f1 = *(const float4*)(src + 4);
      u16x8 v;
      v[0] = f2bf(f0.x); v[1] = f2bf(f0.y); v[2] = f2bf(f0.z); v[3] = f2bf(f0.w);
      v[4] = f2bf(f1.x); v[5] = f2bf(f1.y); v[6] = f2bf(f1.z); v[7] = f2bf(f1.w);
      *(u16x8*)(As + row * 128 + c8 * 16) = v;
    }
#pragma unroll
    for (int it = 0; it < 4; ++it) {
      int ch = it * 256 + tid;
      int row = ch >> 3, kp = ch & 7;
      uint32_t w = wq[(size_t)(bn0 + row) * KP + kt * 8 + kp];
      float s = sv[it], z = zv[it];
      u16x8 v;
#pragma unroll
      for (int j = 0; j < 8; ++j) {
        float qf = (float)((w >> (4 * j)) & 0xF);
        float t  = bf16r(qf * s);
        v[j] = f2bf(t + z);
      }
      *(u16x8*)(Bs + row * 128 + kp * 16) = v;
    }
    __syncthreads();
#pragma unroll
    for (int ks = 0; ks < 2; ++ks) {
      bf16x8 af[4], bf[4];
#pragma unroll
      for (int i = 0; i < 4; ++i)
        af[i] = *(const bf16x8*)(As + base_a + i * 2048 + ks * 64);
#pragma unroll
      for (int j = 0; j < 4; ++j)
        bf[j] = *(const bf16x8*)(Bs + base_b + j * 2048 + ks * 64);
#pragma unroll
      for (int i = 0; i < 4; ++i)
#pragma unroll
        for (int j = 0; j < 4; ++j)
          acc[i][j] = __builtin_amdgcn_mfma_f32_16x16x32_bf16(af[i], bf[j],
                                                              acc[i][j], 0, 0, 0);
    }
  }

  const int colbase = bn0 + wn * 64 + (lane & 15);
  const int rowbase = bm0 + wm * 64 + ((lane >> 4) << 2);
  float bv[4];
#pragma unroll
  for (int j = 0; j < 4; ++j) bv[j] = bias[colbase + j * 16];
#pragma unroll
  for (int i = 0; i < 4; ++i) {
#pragma unroll
    for (int j = 0; j < 4; ++j) {
      size_t base = (size_t)(rowbase + i * 16) * NDIM + colbase + j * 16;
#pragma unroll
      for (int r = 0; r < 4; ++r)
        out[base + (size_t)r * NDIM] = acc[i][j][r] + bv[j];
    }
  }
}

extern "C" void kernel_launch(void* const* d_in, const int* in_sizes, int n_in,
                              void* d_out, int out_size, void* d_ws, size_t ws_size,
                              hipStream_t stream) {
  const float*    x      = (const float*)d_in[0];
  const uint32_t* wq     = (const uint32_t*)d_in[1];
  const float*    scales = (const float*)d_in[2];
  const float*    zeros  = (const float*)d_in[3];
  const float*    bias   = (const float*)d_in[4];
  float*          out    = (float*)d_out;

  const size_t needW = (size_t)NDIM * KDIM * 2;  // 90,177,536 B
  const size_t needX = (size_t)MDIM * KDIM * 2;  // 33,554,432 B

  if (ws_size >= needW + needX) {
    unsigned short* Wbf = (unsigned short*)d_ws;
    unsigned short* Xbf = (unsigned short*)((char*)d_ws + needW);
    dequant_w_kernel<<<(NDIM * KP) / 256, 256, 0, stream>>>(wq, scales, zeros,
                                                            (u16x8*)Wbf);
    convert_x_kernel<<<(MDIM * KDIM / 8) / 256, 256, 0, stream>>>(
        (const float4*)x, (u16x8*)Xbf);
    gemm256_kernel<<<688, 512, 0, stream>>>(Xbf, Wbf, bias, out);
  } else {
    gemm_fused_kernel<<<2752, 256, 0, stream>>>(x, wq, scales, zeros, bias, out);
  }
}